// Round 5
// baseline (210.333 us; speedup 1.0000x reference)
//
#include <hip/hip_runtime.h>

#define N_NODES 50000
#define N_EDGES 800000

__device__ __forceinline__ float lrelu(float v) { return v >= 0.f ? v : 0.01f * v; }

// ---- scanA: f1 = in-nbrs(node 1) + record dst==1 edges; agg0 (unfiltered scalar agg) ----
__global__ void scanA(const float* __restrict__ x, const int* __restrict__ src,
                      const int* __restrict__ dst, unsigned char* __restrict__ f1,
                      int* __restrict__ e1src, int* __restrict__ cntE1,
                      float* __restrict__ agg0, int nE) {
    int e = blockIdx.x * blockDim.x + threadIdx.x;
    if (e < nE) {
        int d = dst[e], s = src[e];
        atomicAdd(&agg0[d], x[s]);
        if (d == 1) { f1[s] = 1; e1src[atomicAdd(cntE1, 1)] = s; }
    }
}

// ---- scanB: f2 = in-nbrs(f1) ----
__global__ void scanB(const int* __restrict__ src, const int* __restrict__ dst,
                      const unsigned char* __restrict__ f1, unsigned char* __restrict__ f2, int nE) {
    int e = blockIdx.x * blockDim.x + threadIdx.x;
    if (e < nE && f1[dst[e]]) f2[src[e]] = 1;
}

// ---- compact lists + zero the agg rows we will actually use ----
__global__ void compact12(const unsigned char* __restrict__ f1, const unsigned char* __restrict__ f2,
                          int* __restrict__ list1, int* __restrict__ cnt1,
                          int* __restrict__ list2, int* __restrict__ cnt2,
                          float* __restrict__ agg1, float* __restrict__ agg2, int n) {
    int i = blockIdx.x * blockDim.x + threadIdx.x;
    if (i < n) {
        if (f1[i]) {
            list1[atomicAdd(cnt1, 1)] = i;
            float* p = agg2 + (size_t)i * 64;
#pragma unroll
            for (int j = 0; j < 64; ++j) p[j] = 0.f;
        }
        if (f2[i]) {
            list2[atomicAdd(cnt2, 1)] = i;
            float* p = agg1 + (size_t)i * 64;
#pragma unroll
            for (int j = 0; j < 64; ++j) p[j] = 0.f;
        }
    }
}

// ---- scanC: agg1[d] += lrelu(agg0[src]*W0 + b0) for edges with f2 dst (h0 on the fly) ----
__global__ void scanC(const float* __restrict__ agg0, const int* __restrict__ src,
                      const int* __restrict__ dst, const unsigned char* __restrict__ f2,
                      const float* __restrict__ W0, const float* __restrict__ b0,
                      float* __restrict__ agg1, int nE) {
    __shared__ float W0s[64], b0s[64];
    if (threadIdx.x < 64) { W0s[threadIdx.x] = W0[threadIdx.x]; b0s[threadIdx.x] = b0[threadIdx.x]; }
    __syncthreads();
    int e = blockIdx.x * blockDim.x + threadIdx.x;
    if (e < nE) {
        int d = dst[e];
        if (f2[d]) {
            float x0 = agg0[src[e]];
            float* ad = agg1 + (size_t)d * 64;
#pragma unroll
            for (int j = 0; j < 64; ++j) atomicAdd(&ad[j], lrelu(x0 * W0s[j] + b0s[j]));
        }
    }
}

// ---- layer12: t2 = (lrelu(agg1@W1+b1))@W2 over list2 nodes (W1/W2 from global/L2) ----
__global__ __launch_bounds__(128) void layer12_k(const float* __restrict__ agg1,
                                                 const int* __restrict__ list2,
                                                 const int* __restrict__ cnt2,
                                                 const float* __restrict__ W1,
                                                 const float* __restrict__ b1,
                                                 const float* __restrict__ W2,
                                                 float* __restrict__ t2) {
    __shared__ float rowA[64];
    __shared__ float rowH[128];
    int tid = threadIdx.x;
    int cnt = *cnt2;
    for (int idx = blockIdx.x; idx < cnt; idx += gridDim.x) {
        int i = list2[idx];
        __syncthreads();
        if (tid < 64) rowA[tid] = agg1[(size_t)i * 64 + tid];
        __syncthreads();
        float acc = b1[tid];
#pragma unroll
        for (int k = 0; k < 64; ++k) acc += rowA[k] * W1[k * 128 + tid];
        rowH[tid] = lrelu(acc);
        __syncthreads();
        if (tid < 64) {
            float a2 = 0.f;
#pragma unroll
            for (int k = 0; k < 128; ++k) a2 += rowH[k] * W2[k * 64 + tid];
            t2[(size_t)i * 64 + tid] = a2;
        }
    }
}

// ---- scanD: agg2[d] += t2[src] for edges with f1 dst ----
__global__ void scanD(const float* __restrict__ t2, const int* __restrict__ src,
                      const int* __restrict__ dst, const unsigned char* __restrict__ f1,
                      float* __restrict__ agg2, int nE) {
    int e = blockIdx.x * blockDim.x + threadIdx.x;
    if (e < nE) {
        int d = dst[e];
        if (f1[d]) {
            const float* xs = t2 + (size_t)src[e] * 64;
            float* ad = agg2 + (size_t)d * 64;
#pragma unroll
            for (int j = 0; j < 64; ++j) atomicAdd(&ad[j], xs[j]);
        }
    }
}

// ---- t3[i] = sum_j lrelu(agg2[i][j]+b2[j])*W3[j] over list1 (one wave per node) ----
__global__ void t3_k(const float* __restrict__ agg2, const int* __restrict__ list1,
                     const int* __restrict__ cnt1, const float* __restrict__ b2,
                     const float* __restrict__ W3, float* __restrict__ t3) {
    int lane = threadIdx.x & 63;
    int wid = (blockIdx.x * blockDim.x + threadIdx.x) >> 6;
    int nw = (gridDim.x * blockDim.x) >> 6;
    int cnt = *cnt1;
    for (int idx = wid; idx < cnt; idx += nw) {
        int i = list1[idx];
        float v = lrelu(agg2[(size_t)i * 64 + lane] + b2[lane]);
        float term = v * W3[lane];
        for (int off = 32; off > 0; off >>= 1) term += __shfl_down(term, off, 64);
        if (lane == 0) t3[i] = term;
    }
}

// ---- final: out = lrelu( sum_{e:dst==1} t3[src[e]] + b3 ) over the recorded edge list ----
__global__ void final_k(const float* __restrict__ t3, const int* __restrict__ e1src,
                        const int* __restrict__ cntE1, const float* __restrict__ b3,
                        float* __restrict__ out) {
    if (threadIdx.x == 0 && blockIdx.x == 0) {
        int c = *cntE1;
        float s = 0.f;
        for (int k = 0; k < c; ++k) s += t3[e1src[k]];
        out[0] = lrelu(s + b3[0]);
    }
}

extern "C" void kernel_launch(void* const* d_in, const int* in_sizes, int n_in,
                              void* d_out, int out_size, void* d_ws, size_t ws_size,
                              hipStream_t stream) {
    const float* in_feat = (const float*)d_in[0];
    const int*   src     = (const int*)d_in[1];
    const int*   dst     = (const int*)d_in[2];
    const float* W0 = (const float*)d_in[3];  const float* b0 = (const float*)d_in[4];
    const float* W1 = (const float*)d_in[5];  const float* b1 = (const float*)d_in[6];
    const float* W2 = (const float*)d_in[7];  const float* b2 = (const float*)d_in[8];
    const float* W3 = (const float*)d_in[9];  const float* b3 = (const float*)d_in[10];
    float* out = (float*)d_out;

    const int n = N_NODES, nE = N_EDGES;
    const int EB = (nE + 255) / 256;

    // ---- workspace: zeroed prefix first ----
    char* base = (char*)d_ws;
    size_t off = 0;
    auto take = [&](size_t bytes) { char* p = base + off; off += (bytes + 255) & ~(size_t)255; return p; };
    unsigned char* f1 = (unsigned char*)take(n);            // zeroed
    unsigned char* f2 = (unsigned char*)take(n);            // zeroed
    float* agg0 = (float*)take((size_t)n * 4);              // zeroed
    int* cnt1  = (int*)take(4);                             // zeroed
    int* cnt2  = (int*)take(4);                             // zeroed
    int* cntE1 = (int*)take(4);                             // zeroed
    size_t zero_bytes = off;
    float* agg1 = (float*)take((size_t)n * 64 * 4);
    float* agg2 = (float*)take((size_t)n * 64 * 4);
    float* t2   = (float*)take((size_t)n * 64 * 4);
    float* t3   = (float*)take((size_t)n * 4);
    int* list1  = (int*)take((size_t)n * 4);
    int* list2  = (int*)take((size_t)n * 4);
    int* e1src  = (int*)take((size_t)n * 4);

    hipMemsetAsync(base, 0, zero_bytes, stream);                                  // ~300 KB

    scanA<<<EB, 256, 0, stream>>>(in_feat, src, dst, f1, e1src, cntE1, agg0, nE); // f1 + agg0
    scanB<<<EB, 256, 0, stream>>>(src, dst, f1, f2, nE);                          // f2
    compact12<<<(n + 255) / 256, 256, 0, stream>>>(f1, f2, list1, cnt1, list2, cnt2,
                                                   agg1, agg2, n);                // lists + row zero
    scanC<<<EB, 256, 0, stream>>>(agg0, src, dst, f2, W0, b0, agg1, nE);          // layer-1 agg
    layer12_k<<<128, 128, 0, stream>>>(agg1, list2, cnt2, W1, b1, W2, t2);        // linear 1+2
    scanD<<<EB, 256, 0, stream>>>(t2, src, dst, f1, agg2, nE);                    // layer-2 agg
    t3_k<<<32, 256, 0, stream>>>(agg2, list1, cnt1, b2, W3, t3);                  // layer-3 linear
    final_k<<<1, 64, 0, stream>>>(t3, e1src, cntE1, b3, out);                     // output
}

// Round 6
// 165.977 us; speedup vs baseline: 1.2672x; 1.2672x over previous
//
#include <hip/hip_runtime.h>

#define N_NODES 50000
#define N_EDGES 800000
#define NE4 (N_EDGES / 4)
#define NMASKW 1568          // ceil(50000/32)=1563, padded
#define MAXN1 192            // LDS accumulator rows in fusedD (deg(node1)~16)

__device__ __forceinline__ float lrelu(float v) { return v >= 0.f ? v : 0.01f * v; }
__device__ __forceinline__ bool mtest(const unsigned int* m, int i) {
    return (m[i >> 5] >> (i & 31)) & 1u;
}

// ---- scan1: edges with dst==1 -> f1 bits + e1src list ----
__global__ void scan1_k(const int4* __restrict__ dst4, const int* __restrict__ src,
                        unsigned int* __restrict__ f1m, int* __restrict__ e1src,
                        int* __restrict__ cntE1) {
    int t = blockIdx.x * blockDim.x + threadIdx.x;
    if (t >= NE4) return;
    int4 d = dst4[t];
    int base = t * 4;
    if (d.x == 1) { int s = src[base + 0]; atomicOr(&f1m[s >> 5], 1u << (s & 31)); e1src[atomicAdd(cntE1, 1)] = s; }
    if (d.y == 1) { int s = src[base + 1]; atomicOr(&f1m[s >> 5], 1u << (s & 31)); e1src[atomicAdd(cntE1, 1)] = s; }
    if (d.z == 1) { int s = src[base + 2]; atomicOr(&f1m[s >> 5], 1u << (s & 31)); e1src[atomicAdd(cntE1, 1)] = s; }
    if (d.w == 1) { int s = src[base + 3]; atomicOr(&f1m[s >> 5], 1u << (s & 31)); e1src[atomicAdd(cntE1, 1)] = s; }
}

// ---- scan2: edges with f1[dst] -> eD list + f2 bits ----
__global__ void scan2_k(const int4* __restrict__ dst4, const int* __restrict__ src,
                        const unsigned int* __restrict__ f1m, unsigned int* __restrict__ f2m,
                        int2* __restrict__ eD, int* __restrict__ cntD) {
    __shared__ unsigned int m[NMASKW];
    for (int k = threadIdx.x; k < NMASKW; k += blockDim.x) m[k] = f1m[k];
    __syncthreads();
    int t = blockIdx.x * blockDim.x + threadIdx.x;
    if (t >= NE4) return;
    int4 d = dst4[t];
    int base = t * 4;
#define DO_EDGE2(dd, off) \
    if (mtest(m, dd)) { int s = src[base + off]; atomicOr(&f2m[s >> 5], 1u << (s & 31)); \
                        eD[atomicAdd(cntD, 1)] = make_int2(s, dd); }
    DO_EDGE2(d.x, 0) DO_EDGE2(d.y, 1) DO_EDGE2(d.z, 2) DO_EDGE2(d.w, 3)
#undef DO_EDGE2
}

// ---- scan3: edges with f2[dst] -> eC list + f3 bits ----
__global__ void scan3_k(const int4* __restrict__ dst4, const int* __restrict__ src,
                        const unsigned int* __restrict__ f2m, unsigned int* __restrict__ f3m,
                        int2* __restrict__ eC, int* __restrict__ cntC) {
    __shared__ unsigned int m[NMASKW];
    for (int k = threadIdx.x; k < NMASKW; k += blockDim.x) m[k] = f2m[k];
    __syncthreads();
    int t = blockIdx.x * blockDim.x + threadIdx.x;
    if (t >= NE4) return;
    int4 d = dst4[t];
    int base = t * 4;
#define DO_EDGE3(dd, off) \
    if (mtest(m, dd)) { int s = src[base + off]; atomicOr(&f3m[s >> 5], 1u << (s & 31)); \
                        eC[atomicAdd(cntC, 1)] = make_int2(s, dd); }
    DO_EDGE3(d.x, 0) DO_EDGE3(d.y, 1) DO_EDGE3(d.z, 2) DO_EDGE3(d.w, 3)
#undef DO_EDGE3
}

// ---- scan4: edges with f3[dst] -> agg0[d] += x[s] ----
__global__ void scan4_k(const int4* __restrict__ dst4, const int* __restrict__ src,
                        const float* __restrict__ x, const unsigned int* __restrict__ f3m,
                        float* __restrict__ agg0) {
    __shared__ unsigned int m[NMASKW];
    for (int k = threadIdx.x; k < NMASKW; k += blockDim.x) m[k] = f3m[k];
    __syncthreads();
    int t = blockIdx.x * blockDim.x + threadIdx.x;
    if (t >= NE4) return;
    int4 d = dst4[t];
    int base = t * 4;
    if (mtest(m, d.x)) atomicAdd(&agg0[d.x], x[src[base + 0]]);
    if (mtest(m, d.y)) atomicAdd(&agg0[d.y], x[src[base + 1]]);
    if (mtest(m, d.z)) atomicAdd(&agg0[d.z], x[src[base + 2]]);
    if (mtest(m, d.w)) atomicAdd(&agg0[d.w], x[src[base + 3]]);
}

// ---- compact: node lists, pos1 map, zero agg1 rows for f2 nodes ----
__global__ void compact_k(const unsigned int* __restrict__ f1m, const unsigned int* __restrict__ f2m,
                          int* __restrict__ list1, int* __restrict__ cnt1, int* __restrict__ pos1,
                          int* __restrict__ list2, int* __restrict__ cnt2,
                          float* __restrict__ agg1) {
    int i = blockIdx.x * blockDim.x + threadIdx.x;
    if (i >= N_NODES) return;
    if (mtest(f1m, i)) { int p = atomicAdd(cnt1, 1); list1[p] = i; pos1[i] = p; }
    if (mtest(f2m, i)) {
        list2[atomicAdd(cnt2, 1)] = i;
        float4* p = (float4*)(agg1 + (size_t)i * 64);
#pragma unroll
        for (int k = 0; k < 16; ++k) p[k] = make_float4(0.f, 0.f, 0.f, 0.f);
    }
}

// ---- aggC: wave per edge, lane per feature: agg1[d][j] += lrelu(agg0[s]*W0[j]+b0[j]) ----
__global__ void aggC_k(const int2* __restrict__ eC, const int* __restrict__ cntC,
                       const float* __restrict__ agg0, const float* __restrict__ W0,
                       const float* __restrict__ b0, float* __restrict__ agg1) {
    int j = threadIdx.x & 63;
    int idx = (blockIdx.x * blockDim.x + threadIdx.x) >> 6;
    int stride = (gridDim.x * blockDim.x) >> 6;
    int cnt = *cntC;
    float w = W0[j], b = b0[j];
    for (; idx < cnt; idx += stride) {
        int2 e = eC[idx];
        float x0 = agg0[e.x];
        atomicAdd(&agg1[(size_t)e.y * 64 + j], lrelu(x0 * w + b));
    }
}

// ---- layer12: t2 = (lrelu(agg1@W1+b1))@W2 over list2 nodes ----
__global__ __launch_bounds__(128) void layer12_k(const float* __restrict__ agg1,
                                                 const int* __restrict__ list2,
                                                 const int* __restrict__ cnt2,
                                                 const float* __restrict__ W1,
                                                 const float* __restrict__ b1,
                                                 const float* __restrict__ W2,
                                                 float* __restrict__ t2) {
    __shared__ float rowA[64];
    __shared__ float rowH[128];
    int tid = threadIdx.x;
    int cnt = *cnt2;
    for (int idx = blockIdx.x; idx < cnt; idx += gridDim.x) {
        int i = list2[idx];
        __syncthreads();
        if (tid < 64) rowA[tid] = agg1[(size_t)i * 64 + tid];
        __syncthreads();
        float acc = b1[tid];
#pragma unroll
        for (int k = 0; k < 64; ++k) acc += rowA[k] * W1[k * 128 + tid];
        rowH[tid] = lrelu(acc);
        __syncthreads();
        if (tid < 64) {
            float a2 = 0.f;
#pragma unroll
            for (int k = 0; k < 128; ++k) a2 += rowH[k] * W2[k * 64 + tid];
            t2[(size_t)i * 64 + tid] = a2;
        }
    }
}

// ---- fusedD: layer-2 agg (LDS acc) + layer-3 linear + final sum + output, 1 block ----
__global__ __launch_bounds__(256) void fusedD_k(const int2* __restrict__ eD, const int* __restrict__ cntD,
                                                const float* __restrict__ t2, const int* __restrict__ pos1,
                                                const int* __restrict__ cnt1, const int* __restrict__ e1src,
                                                const int* __restrict__ cntE1, const float* __restrict__ b2,
                                                const float* __restrict__ W3, const float* __restrict__ b3,
                                                float* __restrict__ out) {
    __shared__ float acc[MAXN1 * 64];   // 48 KB
    __shared__ float t3s[MAXN1];
    int tid = threadIdx.x;
    int c1 = *cnt1, cD = *cntD, cE = *cntE1;
    for (int k = tid; k < c1 * 64; k += 256) acc[k] = 0.f;
    __syncthreads();
    int j = tid & 63, widx = tid >> 6;           // 4 waves
#pragma unroll 4
    for (int idx = widx; idx < cD; idx += 4) {
        int2 e = eD[idx];
        float v = t2[(size_t)e.x * 64 + j];
        atomicAdd(&acc[pos1[e.y] * 64 + j], v);
    }
    __syncthreads();
    for (int slot = widx; slot < c1; slot += 4) {
        float v = lrelu(acc[slot * 64 + j] + b2[j]) * W3[j];
        for (int off = 32; off > 0; off >>= 1) v += __shfl_down(v, off, 64);
        if (j == 0) t3s[slot] = v;
    }
    __syncthreads();
    if (tid < 64) {
        float s = 0.f;
        for (int k = tid; k < cE; k += 64) s += t3s[pos1[e1src[k]]];
        for (int off = 32; off > 0; off >>= 1) s += __shfl_down(s, off, 64);
        if (tid == 0) out[0] = lrelu(s + b3[0]);
    }
}

extern "C" void kernel_launch(void* const* d_in, const int* in_sizes, int n_in,
                              void* d_out, int out_size, void* d_ws, size_t ws_size,
                              hipStream_t stream) {
    const float* in_feat = (const float*)d_in[0];
    const int*   src     = (const int*)d_in[1];
    const int*   dst     = (const int*)d_in[2];
    const float* W0 = (const float*)d_in[3];  const float* b0 = (const float*)d_in[4];
    const float* W1 = (const float*)d_in[5];  const float* b1 = (const float*)d_in[6];
    const float* W2 = (const float*)d_in[7];  const float* b2 = (const float*)d_in[8];
    const float* W3 = (const float*)d_in[9];  const float* b3 = (const float*)d_in[10];
    float* out = (float*)d_out;
    const int4* dst4 = (const int4*)dst;

    // ---- workspace: zeroed prefix first ----
    char* base = (char*)d_ws;
    size_t off = 0;
    auto take = [&](size_t bytes) { char* p = base + off; off += (bytes + 255) & ~(size_t)255; return p; };
    unsigned int* f1m = (unsigned int*)take(NMASKW * 4);      // zeroed
    unsigned int* f2m = (unsigned int*)take(NMASKW * 4);      // zeroed
    unsigned int* f3m = (unsigned int*)take(NMASKW * 4);      // zeroed
    int* cntE1 = (int*)take(4);                               // zeroed
    int* cntD  = (int*)take(4);                               // zeroed
    int* cntC  = (int*)take(4);                               // zeroed
    int* cnt1  = (int*)take(4);                               // zeroed
    int* cnt2  = (int*)take(4);                               // zeroed
    float* agg0 = (float*)take((size_t)N_NODES * 4);          // zeroed
    size_t zero_bytes = off;
    float* agg1 = (float*)take((size_t)N_NODES * 64 * 4);
    float* t2   = (float*)take((size_t)N_NODES * 64 * 4);
    int*  e1src = (int*)take((size_t)N_NODES * 4);
    int2* eD    = (int2*)take((size_t)N_EDGES * 8);
    int2* eC    = (int2*)take((size_t)N_EDGES * 8);
    int*  list1 = (int*)take((size_t)N_NODES * 4);
    int*  list2 = (int*)take((size_t)N_NODES * 4);
    int*  pos1  = (int*)take((size_t)N_NODES * 4);

    const int SB = (NE4 + 255) / 256;   // 782 blocks

    hipMemsetAsync(base, 0, zero_bytes, stream);                                   // ~220 KB
    scan1_k<<<SB, 256, 0, stream>>>(dst4, src, f1m, e1src, cntE1);                 // f1 + e1 edges
    scan2_k<<<SB, 256, 0, stream>>>(dst4, src, f1m, f2m, eD, cntD);                // f2 + eD list
    compact_k<<<(N_NODES + 255) / 256, 256, 0, stream>>>(f1m, f2m, list1, cnt1,
                                                          pos1, list2, cnt2, agg1);
    scan3_k<<<SB, 256, 0, stream>>>(dst4, src, f2m, f3m, eC, cntC);                // f3 + eC list
    scan4_k<<<SB, 256, 0, stream>>>(dst4, src, in_feat, f3m, agg0);                // agg0 (filtered)
    aggC_k<<<256, 256, 0, stream>>>(eC, cntC, agg0, W0, b0, agg1);                 // layer-1 agg
    layer12_k<<<128, 128, 0, stream>>>(agg1, list2, cnt2, W1, b1, W2, t2);         // linear 1+2
    fusedD_k<<<1, 256, 0, stream>>>(eD, cntD, t2, pos1, cnt1, e1src, cntE1,
                                    b2, W3, b3, out);                              // tail fused
}